// Round 3
// baseline (437.607 us; speedup 1.0000x reference)
//
#include <hip/hip_runtime.h>

// Inputs: M (f32, 2048x4096), params (f32, 4096), kinds (int32, 4096).
// Output: f32, 10240x10240. (Harness compares vs a bf16-recomputed np ref
// with a 2%*max threshold — f32 output passes trivially.)
#define NN 2048              // N_NODES
#define EE 4096              // N_ELEMS
#define WW 10240             // 2*E + N columns
#define TOT_ROWS 10240       // N + 2*E rows

typedef float v4f __attribute__((ext_vector_type(4)));

#define TP_BLOCKS (64 * 32)               // 64x64 transpose tiles over M
#define V4_PER_ROW (WW / 4)               // 2560 (each wave stays in one row;
                                          // col boundaries 4096/8192 are wave-aligned)
#define FILL_BLOCKS (TOT_ROWS * V4_PER_ROW / 256)   // 102400

// One fused kernel:
//  blocks [0, 2048):   64x64 tile of M -> straight copy (rows [0,N), cols [0,E))
//                      and -M^T (rows [N,N+E), cols [2E,W)), one M read total.
//  blocks [2048, ...): streaming fill of everything else (zeros, I_E, z/y diag).
// Every output element is written exactly once (out is re-poisoned each call).
__global__ __launch_bounds__(256) void coeff_kernel(
    const float* __restrict__ M,
    const float* __restrict__ params,
    const int*   __restrict__ kinds,
    float*       __restrict__ out)
{
    int tid = threadIdx.x;

    if (blockIdx.x < TP_BLOCKS) {
        // t[c*64 + (r ^ 4*(c&15))] = M[rTile+r][cTile+c]  (XOR swizzle:
        // scalar scatter-writes land <=2-way per bank with the s-rotation;
        // float4 reads stay contiguous since the XOR value is 4-aligned)
        __shared__ __align__(16) float t[64 * 64];
        int cTile = (blockIdx.x & 63) << 6;   // M col base (output row e base)
        int rTile = (blockIdx.x >> 6) << 6;   // M row base (output col j base)
        int r = tid & 15, q = tid >> 4;
        int c0 = r * 4;

        #pragma unroll
        for (int it = 0; it < 4; ++it) {
            int lrow = it * 16 + q;           // M row within tile
            v4f val = *(const v4f*)(M + (size_t)(rTile + lrow) * EE + cTile + c0);
            // straight copy block: out[rTile+lrow][cTile+c0 ..]
            *(v4f*)(out + (size_t)(rTile + lrow) * WW + cTile + c0) = val;
            #pragma unroll
            for (int s = 0; s < 4; ++s) {
                int i = (s + (r >> 2)) & 3;   // rotate to spread banks
                int c = c0 + i;               // M col within tile
                t[c * 64 + (lrow ^ ((c & 15) * 4))] = val[i];
            }
        }
        __syncthreads();

        #pragma unroll
        for (int it = 0; it < 4; ++it) {
            int e  = it * 16 + q;             // output row within tile (M col)
            int j0 = r * 4;                   // output col within tile (M row)
            v4f v = *(const v4f*)(t + e * 64 + (j0 ^ ((e & 15) * 4)));
            v4f nv = { -v[0], -v[1], -v[2], -v[3] };
            *(v4f*)(out + (size_t)(NN + cTile + e) * WW + 2 * EE + rTile + j0) = nv;
        }
    } else {
        int idx = (blockIdx.x - TP_BLOCKS) * 256 + tid;   // < 10240*2560
        int row = idx / V4_PER_ROW;                       // magic-mul divide
        int c4  = idx - row * V4_PER_ROW;
        int col = c4 * 4;

        v4f v = {0.f, 0.f, 0.f, 0.f};

        if (row < NN) {
            if (col < EE) return;             // transpose tiles own the M copy
            // [E, W): zeros
        } else if (row < NN + EE) {
            if (col >= 2 * EE) return;        // transpose tiles own -M^T
            int e = row - NN;
            unsigned d = (unsigned)(EE + e - col);
            if (d < 4u) v[d] = 1.0f;          // I_E at (e, E+e)
        } else {
            int e = row - (NN + EE);          // wave-uniform (wave within a row)
            float p = params[e];
            int k = kinds[e];
            bool on = p > 0.0f;
            float z, y;
            if (k == 0)      { z = -p;            y = 1.0f; }  // R
            else if (k == 1) { z = 0.0f;          y = 1.0f; }  // IVS
            else if (k == 2) { z = 1.0f;          y = 0.0f; }  // VC
            else             { z = on ? 0.f : 1.f; y = on ? 1.f : 0.f; } // SW
            unsigned dz = (unsigned)(e - col);
            if (dz < 4u) v[dz] = z;
            unsigned dy = (unsigned)(EE + e - col);
            if (dy < 4u) v[dy] = y;
        }

        *(v4f*)(out + (size_t)row * WW + col) = v;
    }
}

extern "C" void kernel_launch(void* const* d_in, const int* in_sizes, int n_in,
                              void* d_out, int out_size, void* d_ws, size_t ws_size,
                              hipStream_t stream) {
    const float* M      = (const float*)d_in[0];   // f32, 2048x4096
    const float* params = (const float*)d_in[1];   // f32, 4096
    const int*   kinds  = (const int*)d_in[2];     // int32, 4096
    float*       out    = (float*)d_out;           // f32, 10240x10240

    coeff_kernel<<<TP_BLOCKS + FILL_BLOCKS, 256, 0, stream>>>(M, params, kinds, out);
}

// Round 4
// 434.184 us; speedup vs baseline: 1.0079x; 1.0079x over previous
//
#include <hip/hip_runtime.h>

// Inputs: M (f32, 2048x4096), params (f32, 4096), kinds (int32, 4096).
// Output: f32, 10240x10240.
#define NN 2048              // N_NODES
#define EE 4096              // N_ELEMS
#define WW 10240             // 2*E + N columns
#define TOT_ROWS 10240       // N + 2*E rows

typedef float v4f __attribute__((ext_vector_type(4)));

#define TP_BLOCKS 2048       // 64x64 transpose tiles over M (64 x 32)

// Fused kernel:
//  blocks [0, 2048):       64x64 tile of M -> straight copy (rows [0,N), cols
//                          [0,E)) and -M^T (rows [N,N+E), cols [2E,W)); one M
//                          read total, 8 x 16B stores per thread.
//  blocks [2048, 12288):   one output ROW per block. Each thread writes 6-10
//                          float4 slots (slot = k*256+tid), so each wave
//                          delivers 6-10 KB per lifetime instead of 1 KB --
//                          amortizes wave-launch overhead (round-3 theory:
//                          1-store waves capped fill BW at ~2.6 TB/s).
// Every output element is written exactly once (out is re-poisoned each call).
__global__ __launch_bounds__(256) void coeff_kernel(
    const float* __restrict__ M,
    const float* __restrict__ params,
    const int*   __restrict__ kinds,
    float*       __restrict__ out)
{
    int tid = threadIdx.x;

    if (blockIdx.x < TP_BLOCKS) {
        // t[c*64 + (r ^ 4*(c&15))] = M[rTile+r][cTile+c]  (XOR swizzle keeps
        // scatter-writes <=2-way per bank; float4 reads stay contiguous since
        // the XOR value is 4-aligned). Verified exact in round 3.
        __shared__ __align__(16) float t[64 * 64];
        int cTile = (blockIdx.x & 63) << 6;   // M col base (output row e base)
        int rTile = (blockIdx.x >> 6) << 6;   // M row base (output col j base)
        int r = tid & 15, q = tid >> 4;
        int c0 = r * 4;

        #pragma unroll
        for (int it = 0; it < 4; ++it) {
            int lrow = it * 16 + q;           // M row within tile
            v4f val = *(const v4f*)(M + (size_t)(rTile + lrow) * EE + cTile + c0);
            // straight copy block: out[rTile+lrow][cTile+c0 ..]
            *(v4f*)(out + (size_t)(rTile + lrow) * WW + cTile + c0) = val;
            #pragma unroll
            for (int s = 0; s < 4; ++s) {
                int i = (s + (r >> 2)) & 3;   // rotate to spread banks
                int c = c0 + i;               // M col within tile
                t[c * 64 + (lrow ^ ((c & 15) * 4))] = val[i];
            }
        }
        __syncthreads();

        #pragma unroll
        for (int it = 0; it < 4; ++it) {
            int e  = it * 16 + q;             // output row within tile (M col)
            int j0 = r * 4;                   // output col within tile (M row)
            v4f v = *(const v4f*)(t + e * 64 + (j0 ^ ((e & 15) * 4)));
            v4f nv = { -v[0], -v[1], -v[2], -v[3] };
            *(v4f*)(out + (size_t)(NN + cTile + e) * WW + 2 * EE + rTile + j0) = nv;
        }
    } else {
        int row = blockIdx.x - TP_BLOCKS;     // [0, 10240)
        float* dst = out + (size_t)row * WW;
        const v4f zero = {0.f, 0.f, 0.f, 0.f};

        if (row < NN) {
            // kcl rows: cols [0,E) owned by transpose tiles; [E,W) zeros.
            // v4 slots [1024, 2560) -> k = 4..9
            #pragma unroll
            for (int k = 4; k < 10; ++k)
                *(v4f*)(dst + (k * 256 + tid) * 4) = zero;
        } else if (row < NN + EE) {
            // kvl rows: [0 | I_E | (-M^T owned by tiles)] -> slots [0, 2048)
            int e = row - NN;
            int col_y = EE + e;               // the single 1.0
            #pragma unroll
            for (int k = 0; k < 8; ++k) {
                int base = (k * 256 + tid) * 4;
                v4f v = zero;
                #pragma unroll
                for (int j = 0; j < 4; ++j)
                    if (base + j == col_y) v[j] = 1.0f;
                *(v4f*)(dst + base) = v;
            }
        } else {
            // elem rows: z at col e, y at col E+e; all 2560 slots.
            int e = row - (NN + EE);
            float p = params[e];
            int kk = kinds[e];
            bool on = p > 0.0f;
            float z, y;
            if (kk == 0)      { z = -p;             y = 1.0f; }          // R
            else if (kk == 1) { z = 0.0f;           y = 1.0f; }          // IVS
            else if (kk == 2) { z = 1.0f;           y = 0.0f; }          // VC
            else              { z = on ? 0.f : 1.f; y = on ? 1.f : 0.f; } // SW
            int col_z = e, col_y = EE + e;
            #pragma unroll
            for (int k = 0; k < 10; ++k) {
                int base = (k * 256 + tid) * 4;
                v4f v = zero;
                #pragma unroll
                for (int j = 0; j < 4; ++j) {
                    if (base + j == col_z) v[j] = z;
                    if (base + j == col_y) v[j] = y;
                }
                *(v4f*)(dst + base) = v;
            }
        }
    }
}

extern "C" void kernel_launch(void* const* d_in, const int* in_sizes, int n_in,
                              void* d_out, int out_size, void* d_ws, size_t ws_size,
                              hipStream_t stream) {
    const float* M      = (const float*)d_in[0];   // f32, 2048x4096
    const float* params = (const float*)d_in[1];   // f32, 4096
    const int*   kinds  = (const int*)d_in[2];     // int32, 4096
    float*       out    = (float*)d_out;           // f32, 10240x10240

    coeff_kernel<<<TP_BLOCKS + TOT_ROWS, 256, 0, stream>>>(M, params, kinds, out);
}